// Round 1
// baseline (863.971 us; speedup 1.0000x reference)
//
#include <hip/hip_runtime.h>

// 2-layer GCN, restructured:
//   ag1[n]  = emb[x_ids[n]] * dinv[n]                       (16f)
//   s1[c]   = dinv[c] * (sum_{r->c} ag1[r] + ag1[c])        (16f)  [CSR gather]
//   y1g[n]  = relu(s1[n] @ W1 + b1) * dinv[n]               (32f)
//   s2[c]   = dinv[c] * (sum_{r->c} y1g[r] + y1g[c])        (32f)  [CSR gather]
//   P[g]    = sum_{batch[n]==g} s2[n]                       (atomic, 256x32)
//   out[g]  = P[g] @ W2 + cnt[g] * b2                       (256x41)

constexpr int BLK = 256;

__global__ __launch_bounds__(BLK) void k_count(const int* __restrict__ col, int E,
                                               int* __restrict__ counts) {
  int e = blockIdx.x * BLK + threadIdx.x;
  if (e < E) atomicAdd(&counts[col[e]], 1);
}

// exclusive scan, part 1: per-block (1024 elements) local scan + block sums
__global__ __launch_bounds__(BLK) void k_scan1(const int* __restrict__ counts, int N,
                                               int* __restrict__ col_ptr,
                                               int* __restrict__ bsum) {
  __shared__ int sd[BLK];
  int tid = threadIdx.x;
  int idx = blockIdx.x * 1024 + tid * 4;
  int c0 = 0, c1 = 0, c2 = 0, c3 = 0;
  if (idx + 3 < N) {
    int4 v = *(const int4*)(counts + idx);
    c0 = v.x; c1 = v.y; c2 = v.z; c3 = v.w;
  } else {
    if (idx + 0 < N) c0 = counts[idx + 0];
    if (idx + 1 < N) c1 = counts[idx + 1];
    if (idx + 2 < N) c2 = counts[idx + 2];
    if (idx + 3 < N) c3 = counts[idx + 3];
  }
  int tsum = c0 + c1 + c2 + c3;
  sd[tid] = tsum;
  __syncthreads();
  for (int off = 1; off < BLK; off <<= 1) {
    int v = (tid >= off) ? sd[tid - off] : 0;
    __syncthreads();
    sd[tid] += v;
    __syncthreads();
  }
  int incl = sd[tid];
  int excl = incl - tsum;
  if (tid == BLK - 1) bsum[blockIdx.x] = incl;
  int run = excl;
  if (idx + 0 < N) { col_ptr[idx + 0] = run; run += c0; }
  if (idx + 1 < N) { col_ptr[idx + 1] = run; run += c1; }
  if (idx + 2 < N) { col_ptr[idx + 2] = run; run += c2; }
  if (idx + 3 < N) { col_ptr[idx + 3] = run; run += c3; }
}

// part 2: scan the (<=128) block sums in one block
__global__ __launch_bounds__(128) void k_scan2(int* __restrict__ bsum, int nb) {
  __shared__ int sd[128];
  int tid = threadIdx.x;
  int v = (tid < nb) ? bsum[tid] : 0;
  sd[tid] = v;
  __syncthreads();
  for (int off = 1; off < 128; off <<= 1) {
    int u = (tid >= off) ? sd[tid - off] : 0;
    __syncthreads();
    sd[tid] += u;
    __syncthreads();
  }
  if (tid < nb) bsum[tid] = sd[tid] - v;  // exclusive
}

// part 3: add block offsets; init cursor and dinv
__global__ __launch_bounds__(BLK) void k_scan3(const int* __restrict__ counts,
                                               const int* __restrict__ bsum, int N, int E,
                                               int* __restrict__ col_ptr,
                                               int* __restrict__ cursor,
                                               float* __restrict__ dinv) {
  int i = blockIdx.x * BLK + threadIdx.x;
  if (i < N) {
    int v = col_ptr[i] + bsum[i >> 10];
    col_ptr[i] = v;
    cursor[i] = v;
    dinv[i] = rsqrtf((float)(counts[i] + 1));  // +1 self-loop; always > 0
    if (i == 0) col_ptr[N] = E;
  }
}

__global__ __launch_bounds__(BLK) void k_fill(const int* __restrict__ row,
                                              const int* __restrict__ col, int E,
                                              int* __restrict__ cursor,
                                              int* __restrict__ edge_row) {
  int e = blockIdx.x * BLK + threadIdx.x;
  if (e < E) {
    int p = atomicAdd(&cursor[col[e]], 1);
    edge_row[p] = row[e];
  }
}

// ag1[n] = emb[x_ids[n]] * dinv[n]; also count nodes per graph
__global__ __launch_bounds__(BLK) void k_prep(const int* __restrict__ x_ids,
                                              const int* __restrict__ batch,
                                              const float* __restrict__ emb,
                                              const float* __restrict__ dinv, int N,
                                              float* __restrict__ ag1,
                                              int* __restrict__ cnt) {
  int t = blockIdx.x * BLK + threadIdx.x;
  int n = t >> 2, ch = t & 3;
  if (n >= N) return;
  float d = dinv[n];
  float4 v = *(const float4*)(emb + (size_t)x_ids[n] * 16 + ch * 4);
  v.x *= d; v.y *= d; v.z *= d; v.w *= d;
  *(float4*)(ag1 + (size_t)n * 16 + ch * 4) = v;
  if (ch == 0) atomicAdd(&cnt[batch[n]], 1);
}

// s1[c] = dinv[c] * (sum ag1[r] + ag1[c]); 4 lanes/node, float4 each
__global__ __launch_bounds__(BLK) void k_agg1(const float* __restrict__ ag1,
                                              const int* __restrict__ col_ptr,
                                              const int* __restrict__ edge_row,
                                              const float* __restrict__ dinv, int N,
                                              float* __restrict__ s1) {
  int t = blockIdx.x * BLK + threadIdx.x;
  int n = t >> 2, ch = t & 3;
  if (n >= N) return;
  int off = ch * 4;
  float4 acc = *(const float4*)(ag1 + (size_t)n * 16 + off);
  int beg = col_ptr[n], end = col_ptr[n + 1];
  for (int i = beg; i < end; ++i) {
    int r = edge_row[i];
    float4 v = *(const float4*)(ag1 + (size_t)r * 16 + off);
    acc.x += v.x; acc.y += v.y; acc.z += v.z; acc.w += v.w;
  }
  float d = dinv[n];
  acc.x *= d; acc.y *= d; acc.z *= d; acc.w *= d;
  *(float4*)(s1 + (size_t)n * 16 + off) = acc;
}

// y1g[n] = relu(s1[n] @ W1 + b1) * dinv[n]; 8 lanes/node, 4 outs each
__global__ __launch_bounds__(BLK) void k_t1(const float* __restrict__ s1,
                                            const float* __restrict__ W1,
                                            const float* __restrict__ b1,
                                            const float* __restrict__ dinv, int N,
                                            float* __restrict__ y1g) {
  __shared__ float W[16 * 32];
  __shared__ float bb[32];
  int tid = threadIdx.x;
  for (int i = tid; i < 512; i += BLK) W[i] = W1[i];
  if (tid < 32) bb[tid] = b1[tid];
  __syncthreads();
  int t = blockIdx.x * BLK + tid;
  int n = t >> 3, ch = t & 7;
  if (n >= N) return;
  const float* sr = s1 + (size_t)n * 16;
  float x[16];
#pragma unroll
  for (int k = 0; k < 16; ++k) x[k] = sr[k];
  int f0 = ch * 4;
  float a0 = bb[f0], a1 = bb[f0 + 1], a2 = bb[f0 + 2], a3 = bb[f0 + 3];
#pragma unroll
  for (int k = 0; k < 16; ++k) {
    float xv = x[k];
    const float* wr = &W[k * 32 + f0];
    a0 += xv * wr[0]; a1 += xv * wr[1]; a2 += xv * wr[2]; a3 += xv * wr[3];
  }
  float d = dinv[n];
  float4 o;
  o.x = fmaxf(a0, 0.f) * d;
  o.y = fmaxf(a1, 0.f) * d;
  o.z = fmaxf(a2, 0.f) * d;
  o.w = fmaxf(a3, 0.f) * d;
  *(float4*)(y1g + (size_t)n * 32 + f0) = o;
}

// s2[c] = dinv[c]*(sum y1g[r] + y1g[c]); pooled directly into P[batch[c]]
__global__ __launch_bounds__(BLK) void k_agg2(const float* __restrict__ y1g,
                                              const int* __restrict__ col_ptr,
                                              const int* __restrict__ edge_row,
                                              const float* __restrict__ dinv,
                                              const int* __restrict__ batch, int N,
                                              float* __restrict__ P) {
  int t = blockIdx.x * BLK + threadIdx.x;
  int n = t >> 3, ch = t & 7;
  if (n >= N) return;
  int off = ch * 4;
  float4 acc = *(const float4*)(y1g + (size_t)n * 32 + off);
  int beg = col_ptr[n], end = col_ptr[n + 1];
  for (int i = beg; i < end; ++i) {
    int r = edge_row[i];
    float4 v = *(const float4*)(y1g + (size_t)r * 32 + off);
    acc.x += v.x; acc.y += v.y; acc.z += v.z; acc.w += v.w;
  }
  float d = dinv[n];
  float* pb = P + (size_t)batch[n] * 32 + off;
  atomicAdd(pb + 0, acc.x * d);
  atomicAdd(pb + 1, acc.y * d);
  atomicAdd(pb + 2, acc.z * d);
  atomicAdd(pb + 3, acc.w * d);
}

// out[g] = P[g] @ W2 + cnt[g] * b2   (256 blocks x 64 threads)
__global__ __launch_bounds__(64) void k_final(const float* __restrict__ P,
                                              const int* __restrict__ cnt,
                                              const float* __restrict__ W2,
                                              const float* __restrict__ b2,
                                              float* __restrict__ out) {
  int g = blockIdx.x;
  int f = threadIdx.x;
  __shared__ float pr[32];
  if (f < 32) pr[f] = P[(size_t)g * 32 + f];
  __syncthreads();
  if (f < 41) {
    float acc = (float)cnt[g] * b2[f];
#pragma unroll
    for (int k = 0; k < 32; ++k) acc += pr[k] * W2[k * 41 + f];
    out[(size_t)g * 41 + f] = acc;
  }
}

extern "C" void kernel_launch(void* const* d_in, const int* in_sizes, int n_in,
                              void* d_out, int out_size, void* d_ws, size_t ws_size,
                              hipStream_t stream) {
  const int* x_ids = (const int*)d_in[0];
  const int* edge_index = (const int*)d_in[1];
  const int* batch = (const int*)d_in[2];
  const float* emb = (const float*)d_in[3];
  const float* W1 = (const float*)d_in[4];
  const float* b1 = (const float*)d_in[5];
  const float* W2 = (const float*)d_in[6];
  const float* b2 = (const float*)d_in[7];
  float* out = (float*)d_out;

  const int N = in_sizes[0];
  const int E = in_sizes[1] / 2;
  const int G = out_size / 41;
  const int* row = edge_index;
  const int* col = edge_index + E;

  char* ws = (char*)d_ws;
  size_t off = 0;
  auto alloc = [&](size_t bytes) -> char* {
    char* p = ws + off;
    off += (bytes + 255) & ~(size_t)255;
    return p;
  };
  int* counts = (int*)alloc((size_t)N * 4);
  int* col_ptr = (int*)alloc(((size_t)N + 1) * 4);
  int* cursor = (int*)alloc((size_t)N * 4);
  float* dinv = (float*)alloc((size_t)N * 4);
  int* edge_row = (int*)alloc((size_t)E * 4);
  float* ag1 = (float*)alloc((size_t)N * 16 * 4);
  float* s1 = (float*)alloc((size_t)N * 16 * 4);
  float* y1g = (float*)alloc((size_t)N * 32 * 4);
  float* P = (float*)alloc((size_t)G * 32 * 4);
  int* cnt = (int*)alloc((size_t)G * 4);
  int nscan = (N + 1023) / 1024;
  int* bsum = (int*)alloc((size_t)nscan * 4);
  (void)ws_size; (void)n_in;

  hipMemsetAsync(counts, 0, (size_t)N * 4, stream);
  hipMemsetAsync(P, 0, (size_t)G * 32 * 4, stream);
  hipMemsetAsync(cnt, 0, (size_t)G * 4, stream);

  k_count<<<(E + BLK - 1) / BLK, BLK, 0, stream>>>(col, E, counts);
  k_scan1<<<nscan, BLK, 0, stream>>>(counts, N, col_ptr, bsum);
  k_scan2<<<1, 128, 0, stream>>>(bsum, nscan);
  k_scan3<<<(N + BLK - 1) / BLK, BLK, 0, stream>>>(counts, bsum, N, E, col_ptr, cursor, dinv);
  k_fill<<<(E + BLK - 1) / BLK, BLK, 0, stream>>>(row, col, E, cursor, edge_row);
  k_prep<<<(N * 4 + BLK - 1) / BLK, BLK, 0, stream>>>(x_ids, batch, emb, dinv, N, ag1, cnt);
  k_agg1<<<(N * 4 + BLK - 1) / BLK, BLK, 0, stream>>>(ag1, col_ptr, edge_row, dinv, N, s1);
  k_t1<<<(N * 8 + BLK - 1) / BLK, BLK, 0, stream>>>(s1, W1, b1, dinv, N, y1g);
  k_agg2<<<(N * 8 + BLK - 1) / BLK, BLK, 0, stream>>>(y1g, col_ptr, edge_row, dinv, batch, N, P);
  k_final<<<G, 64, 0, stream>>>(P, cnt, W2, b2, out);
}